// Round 1
// baseline (404.798 us; speedup 1.0000x reference)
//
#include <hip/hip_runtime.h>
#include <hip/hip_bf16.h>
#include <stdint.h>

#define WIDTH 4096
#define NROWS 8192
#define NHEADS 8
#define BW 512
#define CS 128
#define NCHUNK (NROWS/CS)

typedef short bf16x8 __attribute__((ext_vector_type(8)));
typedef float f32x4 __attribute__((ext_vector_type(4)));

__device__ __forceinline__ uint32_t rne_bf16(float f) {
  uint32_t u = __float_as_uint(f);
  return (u + 0x7fffu + ((u >> 16) & 1u)) >> 16;
}
__device__ __forceinline__ uint32_t pack2(float lo, float hi) {
  return rne_bf16(lo) | (rne_bf16(hi) << 16);
}

// ---- prep: transpose weights f32 [h][i][j] -> bf16 [g*8+h][j][i] ----
__global__ void prep_weights(const float* __restrict__ ig_w,
                             const float* __restrict__ ag_w,
                             uint16_t* __restrict__ wt) {
  __shared__ float tile[32][33];
  int j0 = blockIdx.x * 32;
  int i0 = blockIdx.y * 32;
  int m  = blockIdx.z;  // g*8+h
  const float* src = ((m >> 3) ? ag_w : ig_w) + (size_t)(m & 7) * BW * BW;
  int tx = threadIdx.x & 31, ty = threadIdx.x >> 5;
  #pragma unroll
  for (int k = 0; k < 4; k++) {
    int i = i0 + ty + 8 * k;
    tile[ty + 8 * k][tx] = src[(size_t)i * BW + (j0 + tx)];
  }
  __syncthreads();
  #pragma unroll
  for (int k = 0; k < 4; k++) {
    int j = j0 + ty + 8 * k;
    wt[((size_t)m * BW + j) * BW + (i0 + tx)] = (uint16_t)rne_bf16(tile[tx][ty + 8 * k]);
  }
}

__global__ void prep_misc(const float* __restrict__ a_param, float* __restrict__ cvec) {
  int i = blockIdx.x * 256 + threadIdx.x;
  if (i < WIDTH) {
    float x = a_param[i];
    float sp = (x > 15.f) ? x : log1pf(expf(x));
    cvec[i] = 8.f * sp;
  }
}

// ---- GEMM: dual-gate bf16 MFMA, tile 128x64, BK=64, fused epilogue ----
#define BM 128
#define BN 64
#define BK 64

__global__ __launch_bounds__(256, 2)
void gates_gemm(const float* __restrict__ x,
                const int* __restrict__ s,
                const uint16_t* __restrict__ wt,
                const float* __restrict__ ig_b,
                const float* __restrict__ ag_b,
                const float* __restrict__ cvec,
                float* __restrict__ a_buf,
                float* __restrict__ nx_out) {
  __shared__ __align__(16) unsigned char smem[32768];  // Xs 16KB + Ws 16KB
  const int nt = blockIdx.x;   // 0..7  (N tile)
  const int mt = blockIdx.y;   // 0..63 (M tile)
  const int h  = blockIdx.z;   // 0..7
  const int m0 = mt * BM;
  const int j0 = nt * BN;
  const int tid = threadIdx.x;
  const int lane = tid & 63;
  const int w = tid >> 6;
  const int lrow = lane & 15;
  const int lkg  = lane >> 4;

  f32x4 acc[2][2][4];
  #pragma unroll
  for (int g = 0; g < 2; g++)
    #pragma unroll
    for (int mf = 0; mf < 2; mf++)
      #pragma unroll
      for (int nf = 0; nf < 4; nf++)
        acc[g][mf][nf] = (f32x4){0.f, 0.f, 0.f, 0.f};

  const int xrow = tid >> 1;
  const int xhalf = tid & 1;
  const float* xsrc = x + (size_t)(m0 + xrow) * WIDTH + h * BW + xhalf * 32;
  const int wg = tid >> 7;
  const int wu = tid & 127;
  const int wrow = wu >> 1;
  const int whalf = wu & 1;
  const uint16_t* wsrc = wt + ((size_t)(wg * 8 + h) * BW + (j0 + wrow)) * BW + whalf * 32;

  for (int kt = 0; kt < 8; kt++) {
    const int k0 = kt * BK;
    __syncthreads();
    {  // stage X (f32 -> bf16, swizzled)
      const float* p = xsrc + k0;
      uint32_t base = (uint32_t)(xrow * 128 + xhalf * 64);
      uint32_t swz = (uint32_t)((xrow & 7) << 4);
      #pragma unroll
      for (int c = 0; c < 4; c++) {
        float4 fa = *reinterpret_cast<const float4*>(p + c * 8);
        float4 fb = *reinterpret_cast<const float4*>(p + c * 8 + 4);
        uint4 v;
        v.x = pack2(fa.x, fa.y); v.y = pack2(fa.z, fa.w);
        v.z = pack2(fb.x, fb.y); v.w = pack2(fb.z, fb.w);
        *reinterpret_cast<uint4*>(smem + ((base + c * 16) ^ swz)) = v;
      }
    }
    {  // stage W (bf16, both gates, swizzled)
      const uint16_t* p = wsrc + k0;
      uint32_t base = (uint32_t)(16384 + wg * 8192 + wrow * 128 + whalf * 64);
      uint32_t swz = (uint32_t)((wrow & 7) << 4);
      #pragma unroll
      for (int c = 0; c < 4; c++) {
        uint4 v = *reinterpret_cast<const uint4*>(p + c * 8);
        *reinterpret_cast<uint4*>(smem + ((base + c * 16) ^ swz)) = v;
      }
    }
    __syncthreads();
    #pragma unroll
    for (int ks = 0; ks < 2; ks++) {
      bf16x8 af[2];
      #pragma unroll
      for (int mf = 0; mf < 2; mf++) {
        int row = 32 * w + 16 * mf + lrow;
        uint32_t addr = (uint32_t)(row * 128 + ks * 64 + lkg * 16);
        addr ^= (uint32_t)((row & 7) << 4);
        af[mf] = *reinterpret_cast<const bf16x8*>(smem + addr);
      }
      #pragma unroll
      for (int g = 0; g < 2; g++) {
        #pragma unroll
        for (int nf = 0; nf < 4; nf++) {
          int j = 16 * nf + lrow;
          uint32_t addr = (uint32_t)(16384 + g * 8192 + j * 128 + ks * 64 + lkg * 16);
          addr ^= (uint32_t)((j & 7) << 4);
          bf16x8 bfr = *reinterpret_cast<const bf16x8*>(smem + addr);
          #pragma unroll
          for (int mf = 0; mf < 2; mf++) {
            acc[g][mf][nf] = __builtin_amdgcn_mfma_f32_16x16x32_bf16(
                af[mf], bfr, acc[g][mf][nf], 0, 0, 0);
          }
        }
      }
    }
  }
  // epilogue: a = exp(-8*sigmoid(yag)*softplus(ap)), nx = x*sigmoid(yig)*mult
  #pragma unroll
  for (int mf = 0; mf < 2; mf++) {
    #pragma unroll
    for (int r = 0; r < 4; r++) {
      int n = m0 + 32 * w + 16 * mf + 4 * lkg + r;
      int sv = s[n];
      int svp = (n > 0) ? s[n - 1] : -1;
      bool reset = (n == 0) || (sv != svp);
      #pragma unroll
      for (int nf = 0; nf < 4; nf++) {
        int j = j0 + 16 * nf + lrow;
        int jj = h * BW + j;
        float yig = acc[0][mf][nf][r] + ig_b[jj];
        float yag = acc[1][mf][nf][r] + ag_b[jj];
        float gx = 1.f / (1.f + expf(-yig));
        float ga = 1.f / (1.f + expf(-yag));
        float la = -ga * cvec[jj];
        float a = expf(la);
        float a2 = expf(2.f * la);
        float mult = reset ? 1.f : sqrtf(fmaxf(1.f - a2, 0.f));
        float xv = x[(size_t)n * WIDTH + jj];
        size_t o = (size_t)n * WIDTH + jj;
        a_buf[o] = a;
        nx_out[o] = xv * gx * mult;
      }
    }
  }
}

// ---- scan phase A: per-chunk carries ----
__global__ void scan_carries(const float* __restrict__ a_buf,
                             const float* __restrict__ nx,
                             float* __restrict__ cA, float* __restrict__ cB) {
  int chunk = blockIdx.x;
  int c = blockIdx.y * 256 + threadIdx.x;
  size_t base = (size_t)chunk * CS * WIDTH + c;
  float pA = 1.f, S = 0.f;
  for (int rb = 0; rb < CS; rb += 8) {
    float av[8], xv[8];
    #pragma unroll
    for (int e = 0; e < 8; e++) {
      size_t o = base + (size_t)(rb + e) * WIDTH;
      av[e] = a_buf[o]; xv[e] = nx[o];
    }
    #pragma unroll
    for (int e = 0; e < 8; e++) { pA *= av[e]; S = av[e] * S + xv[e]; }
  }
  cA[chunk * WIDTH + c] = pA;
  cB[chunk * WIDTH + c] = S;
}

// ---- scan phase B: prefix over chunks ----
__global__ void scan_prefix(const float* __restrict__ cA, const float* __restrict__ cB,
                            float* __restrict__ prefix) {
  int c = blockIdx.x * 256 + threadIdx.x;
  float hcur = 0.f;
  for (int i0 = 0; i0 < NCHUNK; i0 += 8) {
    float av[8], bv[8];
    #pragma unroll
    for (int e = 0; e < 8; e++) { av[e] = cA[(i0 + e) * WIDTH + c]; bv[e] = cB[(i0 + e) * WIDTH + c]; }
    #pragma unroll
    for (int e = 0; e < 8; e++) { prefix[(i0 + e) * WIDTH + c] = hcur; hcur = av[e] * hcur + bv[e]; }
  }
}

// ---- scan phase C: apply (in place on d_out) ----
__global__ void scan_apply(const float* __restrict__ a_buf,
                           const float* __restrict__ prefix,
                           float* __restrict__ out) {
  int chunk = blockIdx.x;
  int c = blockIdx.y * 256 + threadIdx.x;
  size_t base = (size_t)chunk * CS * WIDTH + c;
  float hcur = prefix[chunk * WIDTH + c];
  for (int rb = 0; rb < CS; rb += 8) {
    float av[8], xv[8];
    #pragma unroll
    for (int e = 0; e < 8; e++) {
      size_t o = base + (size_t)(rb + e) * WIDTH;
      av[e] = a_buf[o]; xv[e] = out[o];
    }
    #pragma unroll
    for (int e = 0; e < 8; e++) { hcur = av[e] * hcur + xv[e]; xv[e] = hcur; }
    #pragma unroll
    for (int e = 0; e < 8; e++) { out[base + (size_t)(rb + e) * WIDTH] = xv[e]; }
  }
}

extern "C" void kernel_launch(void* const* d_in, const int* in_sizes, int n_in,
                              void* d_out, int out_size, void* d_ws, size_t ws_size,
                              hipStream_t stream) {
  const float* x       = (const float*)d_in[0];
  const int*   s       = (const int*)d_in[1];
  const float* a_param = (const float*)d_in[2];
  const float* ig_w    = (const float*)d_in[3];
  const float* ig_b    = (const float*)d_in[4];
  const float* ag_w    = (const float*)d_in[5];
  const float* ag_b    = (const float*)d_in[6];
  float* out = (float*)d_out;
  char* ws = (char*)d_ws;

  float*    a_buf  = (float*)ws;                          // 134217728 B
  uint16_t* wt     = (uint16_t*)(ws + 134217728);         //   8388608 B
  float*    cvec   = (float*)(ws + 142606336);            //     16384 B
  float*    cA     = (float*)(ws + 142622720);            //   1048576 B
  float*    cB     = (float*)(ws + 143671296);            //   1048576 B
  float*    prefix = (float*)(ws + 144719872);            //   1048576 B

  prep_weights<<<dim3(16, 16, 16), 256, 0, stream>>>(ig_w, ag_w, wt);
  prep_misc<<<dim3(16), 256, 0, stream>>>(a_param, cvec);
  gates_gemm<<<dim3(8, 64, 8), 256, 0, stream>>>(x, s, wt, ig_b, ag_b, cvec, a_buf, out);
  scan_carries<<<dim3(NCHUNK, 16), 256, 0, stream>>>(a_buf, out, cA, cB);
  scan_prefix<<<dim3(16), 256, 0, stream>>>(cA, cB, prefix);
  scan_apply<<<dim3(NCHUNK, 16), 256, 0, stream>>>(a_buf, prefix, out);
}

// Round 2
// 289.537 us; speedup vs baseline: 1.3981x; 1.3981x over previous
//
#include <hip/hip_runtime.h>
#include <hip/hip_bf16.h>
#include <stdint.h>

#define WIDTH 4096
#define NROWS 8192
#define NHEADS 8
#define BW 512
#define CS 128
#define NCHUNK (NROWS/CS)

typedef short bf16x8 __attribute__((ext_vector_type(8)));
typedef float f32x4 __attribute__((ext_vector_type(4)));

__device__ __forceinline__ uint32_t rne_bf16(float f) {
  uint32_t u = __float_as_uint(f);
  return (u + 0x7fffu + ((u >> 16) & 1u)) >> 16;
}
__device__ __forceinline__ uint32_t pack2(float lo, float hi) {
  return rne_bf16(lo) | (rne_bf16(hi) << 16);
}

__device__ __forceinline__ void gload_lds16(const void* g, void* l) {
  __builtin_amdgcn_global_load_lds(
      (const __attribute__((address_space(1))) void*)g,
      (__attribute__((address_space(3))) void*)l, 16, 0, 0);
}

// ---- prep: x f32 -> bf16 ----
__global__ void prep_xbf16(const float* __restrict__ x, uint16_t* __restrict__ xb) {
  size_t i = ((size_t)blockIdx.x * 256 + threadIdx.x) * 8;
  float4 f0 = *reinterpret_cast<const float4*>(x + i);
  float4 f1 = *reinterpret_cast<const float4*>(x + i + 4);
  uint4 v;
  v.x = pack2(f0.x, f0.y); v.y = pack2(f0.z, f0.w);
  v.z = pack2(f1.x, f1.y); v.w = pack2(f1.z, f1.w);
  *reinterpret_cast<uint4*>(xb + i) = v;
}

// ---- prep: transpose weights f32 [h][i][j] -> bf16 [g*8+h][j][i] ----
__global__ void prep_weights(const float* __restrict__ ig_w,
                             const float* __restrict__ ag_w,
                             uint16_t* __restrict__ wt) {
  __shared__ float tile[32][33];
  int j0 = blockIdx.x * 32;
  int i0 = blockIdx.y * 32;
  int m  = blockIdx.z;  // g*8+h
  const float* src = ((m >> 3) ? ag_w : ig_w) + (size_t)(m & 7) * BW * BW;
  int tx = threadIdx.x & 31, ty = threadIdx.x >> 5;
  #pragma unroll
  for (int k = 0; k < 4; k++) {
    int i = i0 + ty + 8 * k;
    tile[ty + 8 * k][tx] = src[(size_t)i * BW + (j0 + tx)];
  }
  __syncthreads();
  #pragma unroll
  for (int k = 0; k < 4; k++) {
    int j = j0 + ty + 8 * k;
    wt[((size_t)m * BW + j) * BW + (i0 + tx)] = (uint16_t)rne_bf16(tile[tx][ty + 8 * k]);
  }
}

__global__ void prep_misc(const float* __restrict__ a_param, float* __restrict__ cvec) {
  int i = blockIdx.x * 256 + threadIdx.x;
  if (i < WIDTH) {
    float x = a_param[i];
    float sp = (x > 15.f) ? x : log1pf(expf(x));
    cvec[i] = 8.f * sp;
  }
}

// ---- GEMM: dual-gate bf16 MFMA, tile 128x128, BK=64, async staging,
//      fused epilogue + fused chunk-carry (scan phase A) ----
#define BM 128
#define BN 128
#define BK 64

__global__ __launch_bounds__(256, 2)
void gates_gemm(const uint16_t* __restrict__ xb,
                const float* __restrict__ x,
                const int* __restrict__ s,
                const uint16_t* __restrict__ wt,
                const float* __restrict__ ig_b,
                const float* __restrict__ ag_b,
                const float* __restrict__ cvec,
                float* __restrict__ a_buf,
                float* __restrict__ nx_out,
                float* __restrict__ cA,
                float* __restrict__ cB) {
  __shared__ __align__(16) unsigned char smem[49152];  // X 16KB @0, W 32KB @16384
  __shared__ unsigned char resetm[BM];

  const int b = blockIdx.x;                    // 0..2047
  const int orig = (b & 7) * 256 + (b >> 3);   // XCD-chunked
  const int h  = orig >> 8;
  const int rem = orig & 255;
  const int mt = rem >> 2;
  const int nt = rem & 3;
  const int m0 = mt * BM;
  const int j0 = nt * BN;

  const int tid = threadIdx.x;
  const int lane = tid & 63;
  const int w = tid >> 6;
  const int wr = w >> 1;
  const int wc = w & 1;
  const int lrow = lane & 15;
  const int lkg  = lane >> 4;

  if (tid < BM) {
    int n = m0 + tid;
    resetm[tid] = (n == 0) || (s[n] != s[n - 1]);
  }

  // per-lane pre-swizzled global source pointers for async staging
  const char* xb_src[4];
  #pragma unroll
  for (int i = 0; i < 4; i++) {
    int o = (4 * w + i) * 1024 + (lane << 4);
    int row = o >> 7;
    int c = (o & 127) ^ ((row & 7) << 4);
    xb_src[i] = (const char*)xb + ((size_t)(m0 + row) * WIDTH + h * BW) * 2 + c;
  }
  const char* w_src[8];
  #pragma unroll
  for (int i = 0; i < 8; i++) {
    int o = (8 * w + i) * 1024 + (lane << 4);
    int g = o >> 14;
    int jl = (o >> 7) & 127;
    int c = (o & 127) ^ ((jl & 7) << 4);
    w_src[i] = (const char*)wt + ((size_t)((g * 8 + h) * BW + (j0 + jl)) * BW) * 2 + c;
  }

  f32x4 acc[2][4][4];
  #pragma unroll
  for (int g = 0; g < 2; g++)
    #pragma unroll
    for (int mf = 0; mf < 4; mf++)
      #pragma unroll
      for (int nf = 0; nf < 4; nf++)
        acc[g][mf][nf] = (f32x4){0.f, 0.f, 0.f, 0.f};

  for (int kt = 0; kt < 8; kt++) {
    __syncthreads();
    #pragma unroll
    for (int i = 0; i < 4; i++)
      gload_lds16(xb_src[i] + kt * 128, smem + (4 * w + i) * 1024);
    #pragma unroll
    for (int i = 0; i < 8; i++)
      gload_lds16(w_src[i] + kt * 128, smem + 16384 + (8 * w + i) * 1024);
    __syncthreads();
    #pragma unroll
    for (int ks = 0; ks < 2; ks++) {
      bf16x8 af[4];
      #pragma unroll
      for (int mf = 0; mf < 4; mf++) {
        int row = wr * 64 + 16 * mf + lrow;
        uint32_t addr = (uint32_t)((row << 7) + ks * 64 + lkg * 16);
        addr ^= (uint32_t)((row & 7) << 4);
        af[mf] = *reinterpret_cast<const bf16x8*>(smem + addr);
      }
      #pragma unroll
      for (int g = 0; g < 2; g++) {
        #pragma unroll
        for (int nf = 0; nf < 4; nf++) {
          int j = wc * 64 + 16 * nf + lrow;
          uint32_t addr = (uint32_t)(16384 + (g << 14) + (j << 7) + ks * 64 + lkg * 16);
          addr ^= (uint32_t)((j & 7) << 4);
          bf16x8 bfr = *reinterpret_cast<const bf16x8*>(smem + addr);
          #pragma unroll
          for (int mf = 0; mf < 4; mf++) {
            acc[g][mf][nf] = __builtin_amdgcn_mfma_f32_16x16x32_bf16(
                af[mf], bfr, acc[g][mf][nf], 0, 0, 0);
          }
        }
      }
    }
  }

  __syncthreads();  // all LDS reads done; smem reused for carry segments below
  float* smf = (float*)smem;  // [2][128] A then [2][128] B (offset 256)

  #pragma unroll
  for (int nf = 0; nf < 4; nf++) {
    int j = j0 + wc * 64 + 16 * nf + lrow;
    int jj = h * BW + j;
    float igb = ig_b[jj], agb = ag_b[jj], cv = cvec[jj];
    float segA[4], segB[4];
    #pragma unroll
    for (int mf = 0; mf < 4; mf++) {
      float A = 1.f, B = 0.f;
      int nbase = m0 + wr * 64 + 16 * mf + 4 * lkg;
      #pragma unroll
      for (int r = 0; r < 4; r++) {
        int n = nbase + r;
        float yig = acc[0][mf][nf][r] + igb;
        float yag = acc[1][mf][nf][r] + agb;
        float gx = __builtin_amdgcn_rcpf(1.f + __expf(-yig));
        float ga = __builtin_amdgcn_rcpf(1.f + __expf(-yag));
        float la = -ga * cv;
        float a = __expf(la);
        float mult = resetm[n - m0] ? 1.f
                     : __builtin_amdgcn_sqrtf(fmaxf(1.f - a * a, 0.f));
        float xv = x[(size_t)n * WIDTH + jj];
        float nx = xv * gx * mult;
        size_t o = (size_t)n * WIDTH + jj;
        a_buf[o] = a;
        nx_out[o] = nx;
        A *= a;
        B = fmaf(a, B, nx);
      }
      segA[mf] = A; segB[mf] = B;
    }
    // combine across lkg (4 segments, stride-16 lanes), order = lkg ascending
    #pragma unroll
    for (int mf = 0; mf < 4; mf++) {
      float A = segA[mf], B = segB[mf];
      #pragma unroll
      for (int d = 16; d <= 32; d <<= 1) {
        float pA = __shfl_xor(A, d, 64);
        float pB = __shfl_xor(B, d, 64);
        bool up = (lane & d) != 0;
        B = up ? fmaf(A, pB, B) : fmaf(pA, B, pB);
        A *= pA;
      }
      segA[mf] = A; segB[mf] = B;
    }
    // serial combine across mf (row order)
    float colA = segA[0], colB = segB[0];
    #pragma unroll
    for (int mf = 1; mf < 4; mf++) {
      colB = fmaf(segA[mf], colB, segB[mf]);
      colA *= segA[mf];
    }
    if (lkg == 0) {
      int clocal = wc * 64 + 16 * nf + lrow;
      smf[wr * 128 + clocal] = colA;
      smf[256 + wr * 128 + clocal] = colB;
    }
  }
  __syncthreads();
  if (tid < BN) {
    float A0 = smf[tid],        B0 = smf[256 + tid];
    float A1 = smf[128 + tid],  B1 = smf[384 + tid];
    float Af = A0 * A1;
    float Bf = fmaf(A1, B0, B1);
    int jj = h * BW + j0 + tid;
    cA[mt * WIDTH + jj] = Af;
    cB[mt * WIDTH + jj] = Bf;
  }
}

// ---- scan phase B: prefix over chunks ----
__global__ void scan_prefix(const float* __restrict__ cA, const float* __restrict__ cB,
                            float* __restrict__ prefix) {
  int c = blockIdx.x * 256 + threadIdx.x;
  float hcur = 0.f;
  for (int i0 = 0; i0 < NCHUNK; i0 += 8) {
    float av[8], bv[8];
    #pragma unroll
    for (int e = 0; e < 8; e++) { av[e] = cA[(i0 + e) * WIDTH + c]; bv[e] = cB[(i0 + e) * WIDTH + c]; }
    #pragma unroll
    for (int e = 0; e < 8; e++) { prefix[(i0 + e) * WIDTH + c] = hcur; hcur = av[e] * hcur + bv[e]; }
  }
}

// ---- scan phase C: apply (in place on d_out) ----
__global__ void scan_apply(const float* __restrict__ a_buf,
                           const float* __restrict__ prefix,
                           float* __restrict__ out) {
  int chunk = blockIdx.x;
  int c = blockIdx.y * 256 + threadIdx.x;
  size_t base = (size_t)chunk * CS * WIDTH + c;
  float hcur = prefix[chunk * WIDTH + c];
  for (int rb = 0; rb < CS; rb += 8) {
    float av[8], xv[8];
    #pragma unroll
    for (int e = 0; e < 8; e++) {
      size_t o = base + (size_t)(rb + e) * WIDTH;
      av[e] = a_buf[o]; xv[e] = out[o];
    }
    #pragma unroll
    for (int e = 0; e < 8; e++) { hcur = av[e] * hcur + xv[e]; xv[e] = hcur; }
    #pragma unroll
    for (int e = 0; e < 8; e++) { out[base + (size_t)(rb + e) * WIDTH] = xv[e]; }
  }
}

extern "C" void kernel_launch(void* const* d_in, const int* in_sizes, int n_in,
                              void* d_out, int out_size, void* d_ws, size_t ws_size,
                              hipStream_t stream) {
  const float* x       = (const float*)d_in[0];
  const int*   s       = (const int*)d_in[1];
  const float* a_param = (const float*)d_in[2];
  const float* ig_w    = (const float*)d_in[3];
  const float* ig_b    = (const float*)d_in[4];
  const float* ag_w    = (const float*)d_in[5];
  const float* ag_b    = (const float*)d_in[6];
  float* out = (float*)d_out;
  char* ws = (char*)d_ws;

  float*    a_buf  = (float*)ws;                        // 134217728 B
  uint16_t* wt     = (uint16_t*)(ws + 134217728);       //   8388608 B
  uint16_t* xb     = (uint16_t*)(ws + 142606336);       //  67108864 B
  float*    cvec   = (float*)(ws + 209715200);          //     16384 B
  float*    cA     = (float*)(ws + 209731584);          //   1048576 B
  float*    cB     = (float*)(ws + 210780160);          //   1048576 B
  float*    prefix = (float*)(ws + 211828736);          //   1048576 B

  prep_xbf16<<<dim3(16384), 256, 0, stream>>>(x, xb);
  prep_weights<<<dim3(16, 16, 16), 256, 0, stream>>>(ig_w, ag_w, wt);
  prep_misc<<<dim3(16), 256, 0, stream>>>(a_param, cvec);
  gates_gemm<<<dim3(2048), 256, 0, stream>>>(xb, x, s, wt, ig_b, ag_b, cvec,
                                             a_buf, out, cA, cB);
  scan_prefix<<<dim3(16), 256, 0, stream>>>(cA, cB, prefix);
  scan_apply<<<dim3(NCHUNK, 16), 256, 0, stream>>>(a_buf, prefix, out);
}

// Round 3
// 240.228 us; speedup vs baseline: 1.6851x; 1.2053x over previous
//
#include <hip/hip_runtime.h>
#include <hip/hip_bf16.h>
#include <stdint.h>

#define WIDTH 4096
#define NROWS 8192
#define NHEADS 8
#define BW 512
#define CS 128
#define NCHUNK (NROWS/CS)

typedef short bf16x8 __attribute__((ext_vector_type(8)));
typedef float f32x4 __attribute__((ext_vector_type(4)));

__device__ __forceinline__ uint32_t rne_bf16(float f) {
  uint32_t u = __float_as_uint(f);
  return (u + 0x7fffu + ((u >> 16) & 1u)) >> 16;
}
__device__ __forceinline__ uint32_t pack2(float lo, float hi) {
  return rne_bf16(lo) | (rne_bf16(hi) << 16);
}
__device__ __forceinline__ float bf16_to_f32(uint32_t bits) {
  return __uint_as_float(bits << 16);
}

__device__ __forceinline__ void gload_lds16(const void* g, void* l) {
  __builtin_amdgcn_global_load_lds(
      (const __attribute__((address_space(1))) void*)g,
      (__attribute__((address_space(3))) void*)l, 16, 0, 0);
}

// ---- prep: x f32 -> bf16 ----
__global__ void prep_xbf16(const float* __restrict__ x, uint16_t* __restrict__ xb) {
  size_t i = ((size_t)blockIdx.x * 256 + threadIdx.x) * 8;
  float4 f0 = *reinterpret_cast<const float4*>(x + i);
  float4 f1 = *reinterpret_cast<const float4*>(x + i + 4);
  uint4 v;
  v.x = pack2(f0.x, f0.y); v.y = pack2(f0.z, f0.w);
  v.z = pack2(f1.x, f1.y); v.w = pack2(f1.z, f1.w);
  *reinterpret_cast<uint4*>(xb + i) = v;
}

// ---- prep: transpose weights f32 [h][i][j] -> bf16 [g*8+h][j][i] ----
__global__ void prep_weights(const float* __restrict__ ig_w,
                             const float* __restrict__ ag_w,
                             uint16_t* __restrict__ wt) {
  __shared__ float tile[32][33];
  int j0 = blockIdx.x * 32;
  int i0 = blockIdx.y * 32;
  int m  = blockIdx.z;  // g*8+h
  const float* src = ((m >> 3) ? ag_w : ig_w) + (size_t)(m & 7) * BW * BW;
  int tx = threadIdx.x & 31, ty = threadIdx.x >> 5;
  #pragma unroll
  for (int k = 0; k < 4; k++) {
    int i = i0 + ty + 8 * k;
    tile[ty + 8 * k][tx] = src[(size_t)i * BW + (j0 + tx)];
  }
  __syncthreads();
  #pragma unroll
  for (int k = 0; k < 4; k++) {
    int j = j0 + ty + 8 * k;
    wt[((size_t)m * BW + j) * BW + (i0 + tx)] = (uint16_t)rne_bf16(tile[tx][ty + 8 * k]);
  }
}

__global__ void prep_misc(const float* __restrict__ a_param, float* __restrict__ cvec) {
  int i = blockIdx.x * 256 + threadIdx.x;
  if (i < WIDTH) {
    float x = a_param[i];
    float sp = (x > 15.f) ? x : log1pf(expf(x));
    cvec[i] = 8.f * sp;
  }
}

// ---- GEMM: dual-gate bf16 MFMA, tile 128x128, BK=64, async staging,
//      fused epilogue (bf16 la/nx out) + fused chunk-carry (scan phase A) ----
#define BM 128
#define BN 128
#define BK 64

__global__ __launch_bounds__(256, 2)
void gates_gemm(const uint16_t* __restrict__ xb,
                const int* __restrict__ s,
                const uint16_t* __restrict__ wt,
                const float* __restrict__ ig_b,
                const float* __restrict__ ag_b,
                const float* __restrict__ cvec,
                uint16_t* __restrict__ la_buf,
                uint16_t* __restrict__ nx_buf,
                float* __restrict__ cA,
                float* __restrict__ cB) {
  __shared__ __align__(16) unsigned char smem[49152];  // X 16KB @0, W 32KB @16384
  __shared__ unsigned char resetm[BM];

  const int b = blockIdx.x;                    // 0..2047
  const int orig = (b & 7) * 256 + (b >> 3);   // XCD-chunked
  const int h  = orig >> 8;
  const int rem = orig & 255;
  const int mt = rem >> 2;
  const int nt = rem & 3;
  const int m0 = mt * BM;
  const int j0 = nt * BN;

  const int tid = threadIdx.x;
  const int lane = tid & 63;
  const int w = tid >> 6;
  const int wr = w >> 1;
  const int wc = w & 1;
  const int lrow = lane & 15;
  const int lkg  = lane >> 4;

  if (tid < BM) {
    int n = m0 + tid;
    resetm[tid] = (n == 0) || (s[n] != s[n - 1]);
  }

  // per-lane pre-swizzled global source pointers for async staging
  const char* xb_src[4];
  #pragma unroll
  for (int i = 0; i < 4; i++) {
    int o = (4 * w + i) * 1024 + (lane << 4);
    int row = o >> 7;
    int c = (o & 127) ^ ((row & 7) << 4);
    xb_src[i] = (const char*)xb + ((size_t)(m0 + row) * WIDTH + h * BW) * 2 + c;
  }
  const char* w_src[8];
  #pragma unroll
  for (int i = 0; i < 8; i++) {
    int o = (8 * w + i) * 1024 + (lane << 4);
    int g = o >> 14;
    int jl = (o >> 7) & 127;
    int c = (o & 127) ^ ((jl & 7) << 4);
    w_src[i] = (const char*)wt + ((size_t)((g * 8 + h) * BW + (j0 + jl)) * BW) * 2 + c;
  }

  f32x4 acc[2][4][4];
  #pragma unroll
  for (int g = 0; g < 2; g++)
    #pragma unroll
    for (int mf = 0; mf < 4; mf++)
      #pragma unroll
      for (int nf = 0; nf < 4; nf++)
        acc[g][mf][nf] = (f32x4){0.f, 0.f, 0.f, 0.f};

  for (int kt = 0; kt < 8; kt++) {
    __syncthreads();
    #pragma unroll
    for (int i = 0; i < 4; i++)
      gload_lds16(xb_src[i] + kt * 128, smem + (4 * w + i) * 1024);
    #pragma unroll
    for (int i = 0; i < 8; i++)
      gload_lds16(w_src[i] + kt * 128, smem + 16384 + (8 * w + i) * 1024);
    __syncthreads();
    #pragma unroll
    for (int ks = 0; ks < 2; ks++) {
      bf16x8 af[4];
      #pragma unroll
      for (int mf = 0; mf < 4; mf++) {
        int row = wr * 64 + 16 * mf + lrow;
        uint32_t addr = (uint32_t)((row << 7) + ks * 64 + lkg * 16);
        addr ^= (uint32_t)((row & 7) << 4);
        af[mf] = *reinterpret_cast<const bf16x8*>(smem + addr);
      }
      #pragma unroll
      for (int g = 0; g < 2; g++) {
        #pragma unroll
        for (int nf = 0; nf < 4; nf++) {
          int j = wc * 64 + 16 * nf + lrow;
          uint32_t addr = (uint32_t)(16384 + (g << 14) + (j << 7) + ks * 64 + lkg * 16);
          addr ^= (uint32_t)((j & 7) << 4);
          bf16x8 bfr = *reinterpret_cast<const bf16x8*>(smem + addr);
          #pragma unroll
          for (int mf = 0; mf < 4; mf++) {
            acc[g][mf][nf] = __builtin_amdgcn_mfma_f32_16x16x32_bf16(
                af[mf], bfr, acc[g][mf][nf], 0, 0, 0);
          }
        }
      }
    }
  }

  __syncthreads();  // all LDS reads done; smem reused for carry segments below
  float* smf = (float*)smem;  // [2][128] A then [2][128] B (offset 256)

  #pragma unroll
  for (int nf = 0; nf < 4; nf++) {
    int j = j0 + wc * 64 + 16 * nf + lrow;
    int jj = h * BW + j;
    float igb = ig_b[jj], agb = ag_b[jj], cv = cvec[jj];
    float segA[4], segB[4];
    #pragma unroll
    for (int mf = 0; mf < 4; mf++) {
      float A = 1.f, B = 0.f;
      int nbase = m0 + wr * 64 + 16 * mf + 4 * lkg;
      #pragma unroll
      for (int r = 0; r < 4; r++) {
        int n = nbase + r;
        size_t o = (size_t)n * WIDTH + jj;
        float yig = acc[0][mf][nf][r] + igb;
        float yag = acc[1][mf][nf][r] + agb;
        float gx = __builtin_amdgcn_rcpf(1.f + __expf(-yig));
        float ga = __builtin_amdgcn_rcpf(1.f + __expf(-yag));
        float la = -ga * cv;
        uint32_t la_bits = rne_bf16(la);
        float la_r = bf16_to_f32(la_bits);
        float a = __expf(la_r);
        float mult = resetm[n - m0] ? 1.f
                     : __builtin_amdgcn_sqrtf(fmaxf(1.f - a * a, 0.f));
        float xv = bf16_to_f32((uint32_t)xb[o]);
        float nx = xv * gx * mult;
        uint32_t nx_bits = rne_bf16(nx);
        float nx_r = bf16_to_f32(nx_bits);
        la_buf[o] = (uint16_t)la_bits;
        nx_buf[o] = (uint16_t)nx_bits;
        A *= a;
        B = fmaf(a, B, nx_r);
      }
      segA[mf] = A; segB[mf] = B;
    }
    // combine across lkg (4 segments, stride-16 lanes), order = lkg ascending
    #pragma unroll
    for (int mf = 0; mf < 4; mf++) {
      float A = segA[mf], B = segB[mf];
      #pragma unroll
      for (int d = 16; d <= 32; d <<= 1) {
        float pA = __shfl_xor(A, d, 64);
        float pB = __shfl_xor(B, d, 64);
        bool up = (lane & d) != 0;
        B = up ? fmaf(A, pB, B) : fmaf(pA, B, pB);
        A *= pA;
      }
      segA[mf] = A; segB[mf] = B;
    }
    // serial combine across mf (row order)
    float colA = segA[0], colB = segB[0];
    #pragma unroll
    for (int mf = 1; mf < 4; mf++) {
      colB = fmaf(segA[mf], colB, segB[mf]);
      colA *= segA[mf];
    }
    if (lkg == 0) {
      int clocal = wc * 64 + 16 * nf + lrow;
      smf[wr * 128 + clocal] = colA;
      smf[256 + wr * 128 + clocal] = colB;
    }
  }
  __syncthreads();
  if (tid < BN) {
    float A0 = smf[tid],        B0 = smf[256 + tid];
    float A1 = smf[128 + tid],  B1 = smf[384 + tid];
    float Af = A0 * A1;
    float Bf = fmaf(A1, B0, B1);
    int jj = h * BW + j0 + tid;
    cA[mt * WIDTH + jj] = Af;
    cB[mt * WIDTH + jj] = Bf;
  }
}

// ---- scan phase B: prefix over chunks ----
__global__ void scan_prefix(const float* __restrict__ cA, const float* __restrict__ cB,
                            float* __restrict__ prefix) {
  int c = blockIdx.x * 256 + threadIdx.x;
  float hcur = 0.f;
  for (int i0 = 0; i0 < NCHUNK; i0 += 8) {
    float av[8], bv[8];
    #pragma unroll
    for (int e = 0; e < 8; e++) { av[e] = cA[(i0 + e) * WIDTH + c]; bv[e] = cB[(i0 + e) * WIDTH + c]; }
    #pragma unroll
    for (int e = 0; e < 8; e++) { prefix[(i0 + e) * WIDTH + c] = hcur; hcur = av[e] * hcur + bv[e]; }
  }
}

// ---- scan phase C: apply (bf16 la/nx in, f32 out) ----
__global__ void scan_apply(const uint16_t* __restrict__ la_buf,
                           const uint16_t* __restrict__ nx_buf,
                           const float* __restrict__ prefix,
                           float* __restrict__ out) {
  int chunk = blockIdx.x;
  int c0 = (blockIdx.y * 256 + threadIdx.x) * 4;
  size_t base = (size_t)chunk * CS * WIDTH + c0;
  float h[4];
  #pragma unroll
  for (int q = 0; q < 4; q++) h[q] = prefix[chunk * WIDTH + c0 + q];
  for (int rb = 0; rb < CS; rb += 4) {
    ushort4 lav[4], nxv[4];
    #pragma unroll
    for (int e = 0; e < 4; e++) {
      size_t o = base + (size_t)(rb + e) * WIDTH;
      lav[e] = *reinterpret_cast<const ushort4*>(la_buf + o);
      nxv[e] = *reinterpret_cast<const ushort4*>(nx_buf + o);
    }
    #pragma unroll
    for (int e = 0; e < 4; e++) {
      float4 ov;
      h[0] = fmaf(__expf(bf16_to_f32(lav[e].x)), h[0], bf16_to_f32(nxv[e].x)); ov.x = h[0];
      h[1] = fmaf(__expf(bf16_to_f32(lav[e].y)), h[1], bf16_to_f32(nxv[e].y)); ov.y = h[1];
      h[2] = fmaf(__expf(bf16_to_f32(lav[e].z)), h[2], bf16_to_f32(nxv[e].z)); ov.z = h[2];
      h[3] = fmaf(__expf(bf16_to_f32(lav[e].w)), h[3], bf16_to_f32(nxv[e].w)); ov.w = h[3];
      *reinterpret_cast<float4*>(out + base + (size_t)(rb + e) * WIDTH) = ov;
    }
  }
}

extern "C" void kernel_launch(void* const* d_in, const int* in_sizes, int n_in,
                              void* d_out, int out_size, void* d_ws, size_t ws_size,
                              hipStream_t stream) {
  const float* x       = (const float*)d_in[0];
  const int*   s       = (const int*)d_in[1];
  const float* a_param = (const float*)d_in[2];
  const float* ig_w    = (const float*)d_in[3];
  const float* ig_b    = (const float*)d_in[4];
  const float* ag_w    = (const float*)d_in[5];
  const float* ag_b    = (const float*)d_in[6];
  float* out = (float*)d_out;
  char* ws = (char*)d_ws;

  uint16_t* la_buf = (uint16_t*)ws;                     //  67108864 B
  uint16_t* nx_buf = (uint16_t*)(ws + 67108864);        //  67108864 B
  uint16_t* wt     = (uint16_t*)(ws + 134217728);       //   8388608 B
  uint16_t* xb     = (uint16_t*)(ws + 142606336);       //  67108864 B
  float*    cvec   = (float*)(ws + 209715200);          //     16384 B
  float*    cA     = (float*)(ws + 209731584);          //   1048576 B
  float*    cB     = (float*)(ws + 210780160);          //   1048576 B
  float*    prefix = (float*)(ws + 211828736);          //   1048576 B

  prep_xbf16<<<dim3(16384), 256, 0, stream>>>(x, xb);
  prep_weights<<<dim3(16, 16, 16), 256, 0, stream>>>(ig_w, ag_w, wt);
  prep_misc<<<dim3(16), 256, 0, stream>>>(a_param, cvec);
  gates_gemm<<<dim3(2048), 256, 0, stream>>>(xb, s, wt, ig_b, ag_b, cvec,
                                             la_buf, nx_buf, cA, cB);
  scan_prefix<<<dim3(16), 256, 0, stream>>>(cA, cB, prefix);
  scan_apply<<<dim3(NCHUNK, 4), 256, 0, stream>>>(la_buf, nx_buf, prefix, out);
}

// Round 4
// 219.494 us; speedup vs baseline: 1.8442x; 1.0945x over previous
//
#include <hip/hip_runtime.h>
#include <hip/hip_bf16.h>
#include <stdint.h>

#define WIDTH 4096
#define NROWS 8192
#define NHEADS 8
#define BW 512
#define CS 128
#define NCHUNK (NROWS/CS)

typedef short bf16x8 __attribute__((ext_vector_type(8)));
typedef float f32x4 __attribute__((ext_vector_type(4)));

__device__ __forceinline__ uint32_t rne_bf16(float f) {
  uint32_t u = __float_as_uint(f);
  return (u + 0x7fffu + ((u >> 16) & 1u)) >> 16;
}
__device__ __forceinline__ uint32_t pack2(float lo, float hi) {
  return rne_bf16(lo) | (rne_bf16(hi) << 16);
}
__device__ __forceinline__ float bf16_to_f32(uint32_t bits) {
  return __uint_as_float(bits << 16);
}

__device__ __forceinline__ void gload_lds16(const void* g, void* l) {
  __builtin_amdgcn_global_load_lds(
      (const __attribute__((address_space(1))) void*)g,
      (__attribute__((address_space(3))) void*)l, 16, 0, 0);
}

// ---- prep: x f32 -> bf16 ----
__global__ void prep_xbf16(const float* __restrict__ x, uint16_t* __restrict__ xb) {
  size_t i = ((size_t)blockIdx.x * 256 + threadIdx.x) * 8;
  float4 f0 = *reinterpret_cast<const float4*>(x + i);
  float4 f1 = *reinterpret_cast<const float4*>(x + i + 4);
  uint4 v;
  v.x = pack2(f0.x, f0.y); v.y = pack2(f0.z, f0.w);
  v.z = pack2(f1.x, f1.y); v.w = pack2(f1.z, f1.w);
  *reinterpret_cast<uint4*>(xb + i) = v;
}

// ---- prep: transpose weights f32 [h][i][j] -> bf16 [g*8+h][j][i] ----
__global__ void prep_weights(const float* __restrict__ ig_w,
                             const float* __restrict__ ag_w,
                             uint16_t* __restrict__ wt) {
  __shared__ float tile[32][33];
  int j0 = blockIdx.x * 32;
  int i0 = blockIdx.y * 32;
  int m  = blockIdx.z;  // g*8+h
  const float* src = ((m >> 3) ? ag_w : ig_w) + (size_t)(m & 7) * BW * BW;
  int tx = threadIdx.x & 31, ty = threadIdx.x >> 5;
  #pragma unroll
  for (int k = 0; k < 4; k++) {
    int i = i0 + ty + 8 * k;
    tile[ty + 8 * k][tx] = src[(size_t)i * BW + (j0 + tx)];
  }
  __syncthreads();
  #pragma unroll
  for (int k = 0; k < 4; k++) {
    int j = j0 + ty + 8 * k;
    wt[((size_t)m * BW + j) * BW + (i0 + tx)] = (uint16_t)rne_bf16(tile[tx][ty + 8 * k]);
  }
}

__global__ void prep_misc(const float* __restrict__ a_param, float* __restrict__ cvec) {
  int i = blockIdx.x * 256 + threadIdx.x;
  if (i < WIDTH) {
    float x = a_param[i];
    float sp = (x > 15.f) ? x : log1pf(expf(x));
    cvec[i] = 8.f * sp;
  }
}

// ---- GEMM: dual-gate bf16 MFMA, tile 256x128, BK=64, 512 thr, dbuf LDS,
//      issue-early staging, fused epilogue (packed la|nx) + chunk carries ----
#define BM 256
#define BN 128
#define BK 64
// per-buffer LDS: X 256*128B = 32KB @0, W 2*128*128B = 32KB @32768; x2 buffers

__global__ __launch_bounds__(512, 2)
void gates_gemm(const uint16_t* __restrict__ xb,
                const int* __restrict__ s,
                const uint16_t* __restrict__ wt,
                const float* __restrict__ ig_b,
                const float* __restrict__ ag_b,
                const float* __restrict__ cvec,
                uint32_t* __restrict__ lanx,
                float* __restrict__ cA,
                float* __restrict__ cB) {
  extern __shared__ __align__(16) unsigned char dsm[];  // 131072 B
  __shared__ unsigned char resetm[BM];

  const int b = blockIdx.x;                    // 0..1023
  const int orig = (b & 7) * 128 + (b >> 3);   // XCD-chunked
  const int h  = orig >> 7;
  const int rem = orig & 127;
  const int mt = rem >> 2;                     // 0..31
  const int nt = rem & 3;                      // 0..3
  const int m0 = mt * BM;
  const int j0 = nt * BN;

  const int tid = threadIdx.x;
  const int lane = tid & 63;
  const int w = tid >> 6;       // 0..7
  const int wr = w >> 1;        // 0..3 (M)
  const int wc = w & 1;         // 0..1 (N)
  const int lrow = lane & 15;
  const int lkg  = lane >> 4;

  if (tid < BM) {
    int n = m0 + tid;
    resetm[tid] = (n == 0) || (s[n] != s[n - 1]);
  }

  // per-lane pre-swizzled global source pointers (swizzle on source, LDS linear)
  const char* xb_src[4];
  #pragma unroll
  for (int i = 0; i < 4; i++) {
    int o = (4 * w + i) * 1024 + (lane << 4);      // [0,32768)
    int row = o >> 7;                              // 0..255
    int c = (o & 127) ^ ((row & 7) << 4);
    xb_src[i] = (const char*)xb + (size_t)(m0 + row) * (WIDTH * 2) + h * (BW * 2) + c;
  }
  const char* w_src[4];
  #pragma unroll
  for (int i = 0; i < 4; i++) {
    int o = (4 * w + i) * 1024 + (lane << 4);      // [0,32768)
    int g = o >> 14;                               // 0..1
    int jl = (o >> 7) & 127;
    int c = (o & 127) ^ ((jl & 7) << 4);
    w_src[i] = (const char*)wt + ((size_t)((g * 8 + h) * BW + (j0 + jl))) * (BW * 2) + c;
  }

  f32x4 acc[2][4][4];
  #pragma unroll
  for (int g = 0; g < 2; g++)
    #pragma unroll
    for (int mf = 0; mf < 4; mf++)
      #pragma unroll
      for (int nf = 0; nf < 4; nf++)
        acc[g][mf][nf] = (f32x4){0.f, 0.f, 0.f, 0.f};

  // prologue: stage kt=0 into buffer 0
  #pragma unroll
  for (int i = 0; i < 4; i++)
    gload_lds16(xb_src[i], dsm + (4 * w + i) * 1024);
  #pragma unroll
  for (int i = 0; i < 4; i++)
    gload_lds16(w_src[i], dsm + 32768 + (4 * w + i) * 1024);
  __syncthreads();  // drains vmcnt

  for (int kt = 0; kt < 8; kt++) {
    const uint32_t cbase = (uint32_t)(kt & 1) << 16;
    if (kt < 7) {  // issue next-tile staging BEFORE compute (overlap)
      const uint32_t nbase = cbase ^ 65536u;
      #pragma unroll
      for (int i = 0; i < 4; i++)
        gload_lds16(xb_src[i] + (kt + 1) * 128, dsm + nbase + (4 * w + i) * 1024);
      #pragma unroll
      for (int i = 0; i < 4; i++)
        gload_lds16(w_src[i] + (kt + 1) * 128, dsm + nbase + 32768 + (4 * w + i) * 1024);
    }
    #pragma unroll
    for (int ks = 0; ks < 2; ks++) {
      bf16x8 af[4];
      #pragma unroll
      for (int mf = 0; mf < 4; mf++) {
        int row = wr * 64 + 16 * mf + lrow;
        uint32_t addr = cbase + (uint32_t)((row << 7) + ks * 64 + lkg * 16);
        addr ^= (uint32_t)((row & 7) << 4);
        af[mf] = *reinterpret_cast<const bf16x8*>(dsm + addr);
      }
      #pragma unroll
      for (int g = 0; g < 2; g++) {
        #pragma unroll
        for (int nf = 0; nf < 4; nf++) {
          int j = wc * 64 + 16 * nf + lrow;
          uint32_t addr = cbase + (uint32_t)(32768 + (g << 14) + (j << 7) + ks * 64 + lkg * 16);
          addr ^= (uint32_t)((j & 7) << 4);
          bf16x8 bfr = *reinterpret_cast<const bf16x8*>(dsm + addr);
          #pragma unroll
          for (int mf = 0; mf < 4; mf++) {
            acc[g][mf][nf] = __builtin_amdgcn_mfma_f32_16x16x32_bf16(
                af[mf], bfr, acc[g][mf][nf], 0, 0, 0);
          }
        }
      }
    }
    __syncthreads();  // drains next-tile loads; protects buffer reuse
  }

  float* smf = (float*)dsm;  // [4][128] A then [4][128] B (offset 512 floats)

  #pragma unroll
  for (int nf = 0; nf < 4; nf++) {
    int j = j0 + wc * 64 + 16 * nf + lrow;
    int jj = h * BW + j;
    float igb = ig_b[jj], agb = ag_b[jj], cv = cvec[jj];
    float segA[4], segB[4];
    #pragma unroll
    for (int mf = 0; mf < 4; mf++) {
      float A = 1.f, B = 0.f;
      int nbase = m0 + wr * 64 + 16 * mf + 4 * lkg;
      #pragma unroll
      for (int r = 0; r < 4; r++) {
        int n = nbase + r;
        size_t o = (size_t)n * WIDTH + jj;
        float yig = acc[0][mf][nf][r] + igb;
        float yag = acc[1][mf][nf][r] + agb;
        float gx = __builtin_amdgcn_rcpf(1.f + __expf(-yig));
        float ga = __builtin_amdgcn_rcpf(1.f + __expf(-yag));
        float la = -ga * cv;
        uint32_t la_bits = rne_bf16(la);
        float la_r = bf16_to_f32(la_bits);
        float a = __expf(la_r);
        float mult = resetm[n - m0] ? 1.f
                     : __builtin_amdgcn_sqrtf(fmaxf(1.f - a * a, 0.f));
        float xv = bf16_to_f32((uint32_t)xb[o]);
        float nx = xv * gx * mult;
        uint32_t nx_bits = rne_bf16(nx);
        float nx_r = bf16_to_f32(nx_bits);
        lanx[o] = la_bits | (nx_bits << 16);
        A *= a;
        B = fmaf(a, B, nx_r);
      }
      segA[mf] = A; segB[mf] = B;
    }
    // combine across lkg (4 segments, stride-16 lanes), order = lkg ascending
    #pragma unroll
    for (int mf = 0; mf < 4; mf++) {
      float A = segA[mf], B = segB[mf];
      #pragma unroll
      for (int d = 16; d <= 32; d <<= 1) {
        float pA = __shfl_xor(A, d, 64);
        float pB = __shfl_xor(B, d, 64);
        bool up = (lane & d) != 0;
        B = up ? fmaf(A, pB, B) : fmaf(pA, B, pB);
        A *= pA;
      }
      segA[mf] = A; segB[mf] = B;
    }
    // serial combine across mf (row order) -> per-wave 64-row carry
    float colA = segA[0], colB = segB[0];
    #pragma unroll
    for (int mf = 1; mf < 4; mf++) {
      colB = fmaf(segA[mf], colB, segB[mf]);
      colA *= segA[mf];
    }
    if (lkg == 0) {
      int clocal = wc * 64 + 16 * nf + lrow;
      smf[wr * 128 + clocal] = colA;
      smf[512 + wr * 128 + clocal] = colB;
    }
  }
  __syncthreads();
  if (tid < 256) {
    int half = tid >> 7;        // 0: rows 0-127 (wr0,1), 1: rows 128-255 (wr2,3)
    int cl = tid & 127;
    int base = half * 2;
    float A0 = smf[base * 128 + cl],       B0 = smf[512 + base * 128 + cl];
    float A1 = smf[(base + 1) * 128 + cl], B1 = smf[512 + (base + 1) * 128 + cl];
    float Af = A0 * A1;
    float Bf = fmaf(A1, B0, B1);
    int ct = mt * 2 + half;
    int jj = h * BW + j0 + cl;
    cA[ct * WIDTH + jj] = Af;
    cB[ct * WIDTH + jj] = Bf;
  }
}

// ---- scan phase B: prefix over chunks ----
__global__ void scan_prefix(const float* __restrict__ cA, const float* __restrict__ cB,
                            float* __restrict__ prefix) {
  int c = blockIdx.x * 256 + threadIdx.x;
  float hcur = 0.f;
  for (int i0 = 0; i0 < NCHUNK; i0 += 8) {
    float av[8], bv[8];
    #pragma unroll
    for (int e = 0; e < 8; e++) { av[e] = cA[(i0 + e) * WIDTH + c]; bv[e] = cB[(i0 + e) * WIDTH + c]; }
    #pragma unroll
    for (int e = 0; e < 8; e++) { prefix[(i0 + e) * WIDTH + c] = hcur; hcur = av[e] * hcur + bv[e]; }
  }
}

// ---- scan phase C: apply (packed la|nx in, f32 out) ----
__global__ void scan_apply(const uint32_t* __restrict__ lanx,
                           const float* __restrict__ prefix,
                           float* __restrict__ out) {
  int chunk = blockIdx.x;
  int c0 = (blockIdx.y * 256 + threadIdx.x) * 4;
  size_t base = (size_t)chunk * CS * WIDTH + c0;
  float h[4];
  #pragma unroll
  for (int q = 0; q < 4; q++) h[q] = prefix[chunk * WIDTH + c0 + q];
  for (int rb = 0; rb < CS; rb += 4) {
    uint4 v[4];
    #pragma unroll
    for (int e = 0; e < 4; e++)
      v[e] = *reinterpret_cast<const uint4*>(lanx + base + (size_t)(rb + e) * WIDTH);
    #pragma unroll
    for (int e = 0; e < 4; e++) {
      float4 ov;
      h[0] = fmaf(__expf(bf16_to_f32(v[e].x & 0xffffu)), h[0], bf16_to_f32(v[e].x >> 16)); ov.x = h[0];
      h[1] = fmaf(__expf(bf16_to_f32(v[e].y & 0xffffu)), h[1], bf16_to_f32(v[e].y >> 16)); ov.y = h[1];
      h[2] = fmaf(__expf(bf16_to_f32(v[e].z & 0xffffu)), h[2], bf16_to_f32(v[e].z >> 16)); ov.z = h[2];
      h[3] = fmaf(__expf(bf16_to_f32(v[e].w & 0xffffu)), h[3], bf16_to_f32(v[e].w >> 16)); ov.w = h[3];
      *reinterpret_cast<float4*>(out + base + (size_t)(rb + e) * WIDTH) = ov;
    }
  }
}

extern "C" void kernel_launch(void* const* d_in, const int* in_sizes, int n_in,
                              void* d_out, int out_size, void* d_ws, size_t ws_size,
                              hipStream_t stream) {
  const float* x       = (const float*)d_in[0];
  const int*   s       = (const int*)d_in[1];
  const float* a_param = (const float*)d_in[2];
  const float* ig_w    = (const float*)d_in[3];
  const float* ig_b    = (const float*)d_in[4];
  const float* ag_w    = (const float*)d_in[5];
  const float* ag_b    = (const float*)d_in[6];
  float* out = (float*)d_out;
  char* ws = (char*)d_ws;

  uint32_t* lanx   = (uint32_t*)ws;                     // 134217728 B
  uint16_t* wt     = (uint16_t*)(ws + 134217728);       //   8388608 B
  uint16_t* xb     = (uint16_t*)(ws + 142606336);       //  67108864 B
  float*    cvec   = (float*)(ws + 209715200);          //     16384 B
  float*    cA     = (float*)(ws + 209731584);          //   1048576 B
  float*    cB     = (float*)(ws + 210780160);          //   1048576 B
  float*    prefix = (float*)(ws + 211828736);          //   1048576 B

  prep_xbf16<<<dim3(16384), 256, 0, stream>>>(x, xb);
  prep_weights<<<dim3(16, 16, 16), 256, 0, stream>>>(ig_w, ag_w, wt);
  prep_misc<<<dim3(16), 256, 0, stream>>>(a_param, cvec);
  gates_gemm<<<dim3(1024), dim3(512), 131072, stream>>>(xb, s, wt, ig_b, ag_b, cvec,
                                                        lanx, cA, cB);
  scan_prefix<<<dim3(16), 256, 0, stream>>>(cA, cB, prefix);
  scan_apply<<<dim3(NCHUNK, 4), 256, 0, stream>>>(lanx, prefix, out);
}